// Round 2
// baseline (267.147 us; speedup 1.0000x reference)
//
#include <hip/hip_runtime.h>

// SNN forward scan: B=64, N=1024, T=512. Row = (b*N+n), x[row*512 + t].
// One thread per row; 64-thread (1-wave) blocks; LDS-staged coalesced I/O.
//
// R2: blocks are exactly one wave -> LDS is wave-private and execution is
// in-order, so __syncthreads() is unnecessary. Removing it matters: the
// compiler lowers __syncthreads to `s_waitcnt vmcnt(0) lgkmcnt(0); s_barrier`,
// which drained every prefetch load each chunk (R1 = 100us, 3.8 TB/s).
// Depth-2 register prefetch (buffers A/B) gives each chunk's loads ~2
// chunk-periods of flight time; compiler emits partial vmcnt waits.
//
// Numerics: must be BIT-EXACT vs the float32 NumPy reference (output is a
// 0/1 threshold — one ulp flip cascades). All mul+add pairs use __fmul_rn/
// __fadd_rn to forbid FMA contraction.
#pragma clang fp contract(off)

#define ROWS    64      // rows per block == threads per block (1 wave)
#define T_LEN   512
#define CHUNK   64      // timesteps staged per tile
#define NCHUNK  (T_LEN / CHUNK)            // 8
#define STRIDE  (CHUNK + 4)                // 68 floats: 16B-aligned rows, balanced banks
#define NVEC    16                         // float4 per thread per chunk
#define NPARAM  1024

__global__ __launch_bounds__(ROWS) void snn_fwd(
    const float* __restrict__ x,
    const float* __restrict__ beta,
    const float* __restrict__ p,
    const float* __restrict__ bparam,
    float* __restrict__ out)
{
    __shared__ float inbuf[ROWS * STRIDE];   // 17,408 B
    __shared__ float outbuf[ROWS * STRIDE];  // 17,408 B  (34.8 KiB -> 4 blocks/CU)

    const int tid     = threadIdx.x;
    const int rowBase = blockIdx.x * ROWS;
    const int n       = (rowBase + tid) & (NPARAM - 1);

    // clamped effective params (clip bounds as float32, same as np)
    const float beta_c = fminf(fmaxf(beta[n], 0.001f), 0.999f);
    const float p_c    = fminf(fabsf(p[n]), 0.999f);
    const float b_c    = fminf(fmaxf(fabsf(bparam[n]), 0.001f), 1.0f);

    // recurrence state
    float mem = 0.0f, refac = 2.0f, a = 0.0f, vth = 1.0f, ps = 0.0f;

    const float4* __restrict__ xv = (const float4*)x;   // row stride = 128 float4
    float4* __restrict__ ov       = (float4*)out;

    // staging map: flat float4 f = it*64 + tid; local row = it*4 + (tid>>4),
    // t4 = tid&15 -> lanes 0..15 cover one row's 256 B contiguously (coalesced).
    const int t4c   = tid & 15;
    const int rquad = tid >> 4;
    const int gq    = (rowBase + rquad) * (T_LEN / 4) + t4c;  // global float4 base
    const int lq    = rquad * STRIDE + t4c * 4;               // LDS float base

    auto loadChunk = [&](int k, float4 (&ld)[NVEC]) {
        const int base = gq + k * (CHUNK / 4);
        #pragma unroll
        for (int it = 0; it < NVEC; ++it)
            ld[it] = xv[base + it * 4 * (T_LEN / 4)];   // +4 rows per it
    };

    auto stage = [&](const float4 (&ld)[NVEC]) {
        #pragma unroll
        for (int it = 0; it < NVEC; ++it)
            *(float4*)&inbuf[lq + it * 4 * STRIDE] = ld[it];
    };

    auto readout = [&](int k) {
        const int base = gq + k * (CHUNK / 4);
        #pragma unroll
        for (int it = 0; it < NVEC; ++it) {
            float4 sv = *(const float4*)&outbuf[lq + it * 4 * STRIDE];
            ov[base + it * 4 * (T_LEN / 4)] = sv;
        }
    };

    // one recurrence step; returns spike (0.0/1.0)
    auto step = [&](float xt) -> float {
        refac = (ps > 0.0f) ? 0.0f : refac;           // spike-triggered reset
        const float ic = (refac < 2.0f) ? 0.0f : xt;  // refractory input mask
        refac += 1.0f;
        const float nm   = __fadd_rn(__fmul_rn(mem, beta_c), ic);  // leaky integrate
        const float diff = __fsub_rn(nm, vth);
        const float s    = (diff > 0.0f) ? 1.0f : 0.0f;
        mem = (diff > 0.0f) ? 0.0f : nm;              // reset-to-zero on spike
        a   = __fadd_rn(__fmul_rn(p_c, a), s);        // adaptation
        vth = __fadd_rn(1.0f, __fmul_rn(b_c, a));     // adaptive threshold
        ps  = s;
        return s;
    };

    const int cbase = tid * STRIDE;

    auto compute = [&]() {
        #pragma unroll
        for (int t4 = 0; t4 < CHUNK / 4; ++t4) {
            float4 xq = *(const float4*)&inbuf[cbase + t4 * 4];
            float4 sv;
            sv.x = step(xq.x);
            sv.y = step(xq.y);
            sv.z = step(xq.z);
            sv.w = step(xq.w);
            *(float4*)&outbuf[cbase + t4 * 4] = sv;
        }
    };

    // depth-2 software pipeline, no barriers (single-wave block, in-order DS)
    float4 A[NVEC], B[NVEC];
    loadChunk(0, A);
    loadChunk(1, B);

    auto half = [&](int k, float4 (&ld)[NVEC]) {
        stage(ld);                               // waits only chunk-k's loads
        if (k + 2 < NCHUNK) loadChunk(k + 2, ld); // refill buffer ~2 periods early
        if (k > 0) readout(k - 1);               // drain previous spike tile
        compute();
    };

    #pragma unroll 1
    for (int k = 0; k < NCHUNK; k += 2) {
        half(k, A);
        half(k + 1, B);
    }
    readout(NCHUNK - 1);
}

extern "C" void kernel_launch(void* const* d_in, const int* in_sizes, int n_in,
                              void* d_out, int out_size, void* d_ws, size_t ws_size,
                              hipStream_t stream) {
    const float* x    = (const float*)d_in[0];
    const float* beta = (const float*)d_in[1];
    const float* p    = (const float*)d_in[2];
    const float* b    = (const float*)d_in[3];
    float* out        = (float*)d_out;

    const int BN = 64 * 1024;  // rows
    snn_fwd<<<dim3(BN / ROWS), dim3(ROWS), 0, stream>>>(x, beta, p, b, out);
}

// Round 5
// 253.648 us; speedup vs baseline: 1.0532x; 1.0532x over previous
//
#include <hip/hip_runtime.h>

// SNN forward scan: B=64, N=1024, T=512. Row = (b*N+n), x[row*512 + t].
//
// R3-R5: wave-specialized producer/consumer. R1/R2 showed ~3.7 TB/s
// regardless of barriers/prefetch: with 1 thread/row the grid gives only
// 4 waves/CU, and a monolithic wave alternates VMEM bursts with LDS+VALU
// chains (0 bytes in flight) -> per-CU BW duty-cycle limited. Split roles:
//   wave0 compute (LDS+VALU only), wave1 load (global->reg->LDS, one chunk
//   ahead), wave2 store (LDS->global), CHUNK=32, double-buffered in/out LDS
// -> 36.9 KB/block, 4 blocks/CU resident = 12 waves/CU, I/O decoupled from
// compute. (R3/R4 benches were container-acquisition infra failures; kernel
// audited: uniform barriers, all indices in bounds, no capture violations.)
//
// Numerics: BIT-EXACT vs float32 NumPy reference (0/1 threshold output —
// one ulp flip cascades). __fmul_rn/__fadd_rn + contract(off).
#pragma clang fp contract(off)

#define ROWS    64                    // rows per block
#define T_LEN   512
#define CHUNK   32                    // timesteps per tile
#define NCHUNK  (T_LEN / CHUNK)       // 16
#define STRIDE  (CHUNK + 4)           // 36 floats: 16B-aligned rows, balanced banks
#define NV      8                     // float4 per io-lane per chunk
#define NPARAM  1024

__global__ __launch_bounds__(192) void snn_fwd(
    const float* __restrict__ x,
    const float* __restrict__ beta,
    const float* __restrict__ p,
    const float* __restrict__ bparam,
    float* __restrict__ out)
{
    __shared__ __align__(16) float inbuf [2][ROWS * STRIDE];  // 2 x 9216 B
    __shared__ __align__(16) float outbuf[2][ROWS * STRIDE];  // 2 x 9216 B (36.9 KB)

    const int tid     = threadIdx.x;
    const int wid     = tid >> 6;       // 0=compute, 1=load, 2=store
    const int lane    = tid & 63;
    const int rowBase = blockIdx.x * ROWS;

    const float4* __restrict__ xv = (const float4*)x;  // row stride 128 float4
    float4* __restrict__ ov       = (float4*)out;

    // io mapping: lane = r8*8 + t8; float4 f: row rowBase+r8+it*8, col k*8+t8.
    // Per instr: 8 segments of 128 B contiguous (2 full lines each).
    const int t8 = lane & 7;
    const int r8 = lane >> 3;
    const int gq = (rowBase + r8) * (T_LEN / 4) + t8;  // + it*8*128 + k*8
    const int lq = r8 * STRIDE + t8 * 4;               // + it*8*STRIDE

    // compute state
    float mem = 0.0f, refac = 2.0f, a = 0.0f, vth = 1.0f, ps = 0.0f;
    float beta_c = 0.f, p_c = 0.f, b_c = 0.f;
    const int cbase = lane * STRIDE;

    if (wid == 0) {
        const int n = (rowBase + lane) & (NPARAM - 1);
        beta_c = fminf(fmaxf(beta[n], 0.001f), 0.999f);
        p_c    = fminf(fabsf(p[n]), 0.999f);
        b_c    = fminf(fmaxf(fabsf(bparam[n]), 0.001f), 1.0f);
    }

    auto step = [&](float xt) -> float {
        refac = (ps > 0.0f) ? 0.0f : refac;           // spike-triggered reset
        const float ic = (refac < 2.0f) ? 0.0f : xt;  // refractory input mask
        refac += 1.0f;
        const float nm   = __fadd_rn(__fmul_rn(mem, beta_c), ic);  // integrate
        const float diff = __fsub_rn(nm, vth);
        const float s    = (diff > 0.0f) ? 1.0f : 0.0f;
        mem = (diff > 0.0f) ? 0.0f : nm;              // reset-to-zero on spike
        a   = __fadd_rn(__fmul_rn(p_c, a), s);        // adaptation
        vth = __fadd_rn(1.0f, __fmul_rn(b_c, a));     // adaptive threshold
        ps  = s;
        return s;
    };

    float4 ld[NV];  // load wave's register pipeline (one chunk ahead)

    auto loadChunk = [&](int k) {
        const int base = gq + k * (CHUNK / 4);
        #pragma unroll
        for (int it = 0; it < NV; ++it)
            ld[it] = xv[base + it * 8 * (T_LEN / 4)];
    };
    auto stage = [&](int buf) {
        #pragma unroll
        for (int it = 0; it < NV; ++it)
            *(float4*)&inbuf[buf][lq + it * 8 * STRIDE] = ld[it];
    };
    auto drain = [&](int buf, int k) {
        float4 sv[NV];
        #pragma unroll
        for (int it = 0; it < NV; ++it)
            sv[it] = *(const float4*)&outbuf[buf][lq + it * 8 * STRIDE];
        const int base = gq + k * (CHUNK / 4);
        #pragma unroll
        for (int it = 0; it < NV; ++it)
            ov[base + it * 8 * (T_LEN / 4)] = sv[it];
    };

    // preamble: chunk 0 staged; chunk 1 in regs (in flight across barrier)
    if (wid == 1) {
        loadChunk(0);
        stage(0);
        loadChunk(1);
    }
    __syncthreads();

    #pragma unroll 1
    for (int k = 0; k < NCHUNK; ++k) {
        const int cur = k & 1;
        if (wid == 0) {
            // compute chunk k: inbuf[cur] -> outbuf[cur]
            #pragma unroll
            for (int t4 = 0; t4 < CHUNK / 4; ++t4) {
                float4 xq = *(const float4*)&inbuf[cur][cbase + t4 * 4];
                float4 sv;
                sv.x = step(xq.x);
                sv.y = step(xq.y);
                sv.z = step(xq.z);
                sv.w = step(xq.w);
                *(float4*)&outbuf[cur][cbase + t4 * 4] = sv;
            }
        } else if (wid == 1) {
            // stage chunk k+1 (regs loaded one chunk ago); refill regs with k+2
            if (k + 1 < NCHUNK) stage(cur ^ 1);
            if (k + 2 < NCHUNK) loadChunk(k + 2);
        } else {
            // drain chunk k-1 (computed last iteration)
            if (k > 0) drain(cur ^ 1, k - 1);
        }
        __syncthreads();
    }
    if (wid == 2) drain(1, NCHUNK - 1);  // chunk 15 lives in outbuf[1]
}

extern "C" void kernel_launch(void* const* d_in, const int* in_sizes, int n_in,
                              void* d_out, int out_size, void* d_ws, size_t ws_size,
                              hipStream_t stream) {
    const float* x    = (const float*)d_in[0];
    const float* beta = (const float*)d_in[1];
    const float* p    = (const float*)d_in[2];
    const float* b    = (const float*)d_in[3];
    float* out        = (float*)d_out;

    const int BN = 64 * 1024;  // rows
    snn_fwd<<<dim3(BN / ROWS), dim3(192), 0, stream>>>(x, beta, p, b, out);
}

// Round 6
// 253.377 us; speedup vs baseline: 1.0543x; 1.0011x over previous
//
#include <hip/hip_runtime.h>

// SNN forward scan: B=64, N=1024, T=512. Row = (b*N+n), x[row*512 + t].
//
// R6: R5's wave-specialized pipeline (compute/load/store waves, CHUNK=32,
// double-buffered LDS, 4 blocks/CU) but with RAW BARRIERS. __syncthreads()
// lowers to `s_waitcnt vmcnt(0) lgkmcnt(0); s_barrier`, which drained the
// load wave's just-issued prefetch (k+2) and the store wave's fresh stores
// at EVERY chunk -> each of 16 chunks paid a full loaded-latency round trip
// (R5: 92us, 3.4 TB/s = 64% of the 310MB-traffic floor). Cross-wave LDS
// visibility needs only lgkmcnt(0): inline-asm barrier skips the vmcnt
// drain, keeping global loads/stores in flight across chunk boundaries.
// Buffer-reuse hazards are safe via per-wave register deps (ds_write waits
// its load's vmcnt; global_store waits its ds_read's lgkmcnt before issue).
//
// Numerics: BIT-EXACT vs float32 NumPy reference (0/1 threshold output —
// one ulp flip cascades). __fmul_rn/__fadd_rn + contract(off).
#pragma clang fp contract(off)

#define ROWS    64                    // rows per block
#define T_LEN   512
#define CHUNK   32                    // timesteps per tile
#define NCHUNK  (T_LEN / CHUNK)       // 16
#define STRIDE  (CHUNK + 4)           // 36 floats: 16B-aligned rows, balanced banks
#define NV      8                     // float4 per io-lane per chunk
#define NPARAM  1024

// lgkmcnt(0)-only barrier: LDS visibility without the vmcnt(0) drain.
#define BARRIER() asm volatile("s_waitcnt lgkmcnt(0)\n\ts_barrier" ::: "memory")

__global__ __launch_bounds__(192) void snn_fwd(
    const float* __restrict__ x,
    const float* __restrict__ beta,
    const float* __restrict__ p,
    const float* __restrict__ bparam,
    float* __restrict__ out)
{
    __shared__ __align__(16) float inbuf [2][ROWS * STRIDE];  // 2 x 9216 B
    __shared__ __align__(16) float outbuf[2][ROWS * STRIDE];  // 2 x 9216 B (36.9 KB)

    const int tid     = threadIdx.x;
    const int wid     = tid >> 6;       // 0=compute, 1=load, 2=store
    const int lane    = tid & 63;
    const int rowBase = blockIdx.x * ROWS;

    const float4* __restrict__ xv = (const float4*)x;  // row stride 128 float4
    float4* __restrict__ ov       = (float4*)out;

    // io mapping: lane = r8*8 + t8; float4 f: row rowBase+r8+it*8, col k*8+t8.
    // Per instr: 8 segments of 128 B contiguous (2 full lines each).
    const int t8 = lane & 7;
    const int r8 = lane >> 3;
    const int gq = (rowBase + r8) * (T_LEN / 4) + t8;  // + it*8*128 + k*8
    const int lq = r8 * STRIDE + t8 * 4;               // + it*8*STRIDE

    // compute state
    float mem = 0.0f, refac = 2.0f, a = 0.0f, vth = 1.0f, ps = 0.0f;
    float beta_c = 0.f, p_c = 0.f, b_c = 0.f;
    const int cbase = lane * STRIDE;

    if (wid == 0) {
        const int n = (rowBase + lane) & (NPARAM - 1);
        beta_c = fminf(fmaxf(beta[n], 0.001f), 0.999f);
        p_c    = fminf(fabsf(p[n]), 0.999f);
        b_c    = fminf(fmaxf(fabsf(bparam[n]), 0.001f), 1.0f);
    }

    auto step = [&](float xt) -> float {
        refac = (ps > 0.0f) ? 0.0f : refac;           // spike-triggered reset
        const float ic = (refac < 2.0f) ? 0.0f : xt;  // refractory input mask
        refac += 1.0f;
        const float nm   = __fadd_rn(__fmul_rn(mem, beta_c), ic);  // integrate
        const float diff = __fsub_rn(nm, vth);
        const float s    = (diff > 0.0f) ? 1.0f : 0.0f;
        mem = (diff > 0.0f) ? 0.0f : nm;              // reset-to-zero on spike
        a   = __fadd_rn(__fmul_rn(p_c, a), s);        // adaptation
        vth = __fadd_rn(1.0f, __fmul_rn(b_c, a));     // adaptive threshold
        ps  = s;
        return s;
    };

    float4 ld[NV];  // load wave's register pipeline (one chunk ahead)

    auto loadChunk = [&](int k) {
        const int base = gq + k * (CHUNK / 4);
        #pragma unroll
        for (int it = 0; it < NV; ++it)
            ld[it] = xv[base + it * 8 * (T_LEN / 4)];
    };
    auto stage = [&](int buf) {
        #pragma unroll
        for (int it = 0; it < NV; ++it)
            *(float4*)&inbuf[buf][lq + it * 8 * STRIDE] = ld[it];
    };
    auto drain = [&](int buf, int k) {
        float4 sv[NV];
        #pragma unroll
        for (int it = 0; it < NV; ++it)
            sv[it] = *(const float4*)&outbuf[buf][lq + it * 8 * STRIDE];
        const int base = gq + k * (CHUNK / 4);
        #pragma unroll
        for (int it = 0; it < NV; ++it)
            ov[base + it * 8 * (T_LEN / 4)] = sv[it];
    };

    // preamble: chunk 0 staged; chunk 1 in regs (in flight across barrier)
    if (wid == 1) {
        loadChunk(0);
        stage(0);
        loadChunk(1);
    }
    BARRIER();

    #pragma unroll 1
    for (int k = 0; k < NCHUNK; ++k) {
        const int cur = k & 1;
        if (wid == 0) {
            // compute chunk k: inbuf[cur] -> outbuf[cur]
            #pragma unroll
            for (int t4 = 0; t4 < CHUNK / 4; ++t4) {
                float4 xq = *(const float4*)&inbuf[cur][cbase + t4 * 4];
                float4 sv;
                sv.x = step(xq.x);
                sv.y = step(xq.y);
                sv.z = step(xq.z);
                sv.w = step(xq.w);
                *(float4*)&outbuf[cur][cbase + t4 * 4] = sv;
            }
        } else if (wid == 1) {
            // stage chunk k+1 (regs loaded one chunk ago); refill regs with k+2
            if (k + 1 < NCHUNK) stage(cur ^ 1);
            if (k + 2 < NCHUNK) loadChunk(k + 2);
        } else {
            // drain chunk k-1 (computed last iteration)
            if (k > 0) drain(cur ^ 1, k - 1);
        }
        BARRIER();
    }
    if (wid == 2) drain(1, NCHUNK - 1);  // chunk 15 lives in outbuf[1]
}

extern "C" void kernel_launch(void* const* d_in, const int* in_sizes, int n_in,
                              void* d_out, int out_size, void* d_ws, size_t ws_size,
                              hipStream_t stream) {
    const float* x    = (const float*)d_in[0];
    const float* beta = (const float*)d_in[1];
    const float* p    = (const float*)d_in[2];
    const float* b    = (const float*)d_in[3];
    float* out        = (float*)d_out;

    const int BN = 64 * 1024;  // rows
    snn_fwd<<<dim3(BN / ROWS), dim3(192), 0, stream>>>(x, beta, p, b, out);
}

// Round 7
// 241.379 us; speedup vs baseline: 1.1068x; 1.0497x over previous
//
#include <hip/hip_runtime.h>

// SNN forward scan: B=64, N=1024, T=512. Row = (b*N+n), x[row*512 + t].
//
// R7: DRAM-pattern attack. R1-R6 all moved 128-B granules at 2-KiB stride
// (32 timesteps x 64 rows per chunk) and all plateau at 3.4-3.9 TB/s (~54%
// of achievable) regardless of barriers/specialization -> the pace is the
// memory system's efficiency for that pattern (page misses + channel
// concentration at stride-16-lines). This version doubles per-row run
// length: CHUNK=64 -> each load/store instr covers 4 rows x 256 B
// CONTIGUOUS (2 full lines per segment). LDS: inbuf x2 + outbuf x1 =
// 49.9 KB (fits 64 KB cap, 3 blocks/CU). Single outbuf is raced-free via
// two phases per chunk: A) store drains chunk k-1 from outbuf, compute
// computes chunk k into registers; lgkm-barrier; B) compute writes spikes
// to outbuf. STRIDE=65 (odd) + b32 LDS ops -> zero bank conflicts.
//
// Numerics: BIT-EXACT vs float32 NumPy reference (0/1 threshold output —
// one ulp flip cascades). __fmul_rn/__fadd_rn + contract(off).
#pragma clang fp contract(off)

#define ROWS    64                    // rows per block (1 compute wave)
#define T_LEN   512
#define CHUNK   64                    // timesteps per tile (256 B/row contiguous)
#define NCHUNK  (T_LEN / CHUNK)       // 8
#define STRIDE  (CHUNK + 1)           // 65: odd -> conflict-free b32 LDS
#define NV      16                    // float4 per io-lane per chunk
#define NPARAM  1024

// lgkmcnt(0)-only barrier: LDS visibility without the vmcnt(0) drain.
#define BARRIER() asm volatile("s_waitcnt lgkmcnt(0)\n\ts_barrier" ::: "memory")

__global__ __launch_bounds__(192) void snn_fwd(
    const float* __restrict__ x,
    const float* __restrict__ beta,
    const float* __restrict__ p,
    const float* __restrict__ bparam,
    float* __restrict__ out)
{
    __shared__ float inbuf[2][ROWS * STRIDE];  // 2 x 16,640 B
    __shared__ float outbuf[ROWS * STRIDE];    //     16,640 B  (49.9 KB total)

    const int tid     = threadIdx.x;
    const int wid     = tid >> 6;       // 0=compute, 1=load, 2=store
    const int lane    = tid & 63;
    const int rowBase = blockIdx.x * ROWS;

    const float4* __restrict__ xv = (const float4*)x;  // row stride 128 float4
    float4* __restrict__ ov       = (float4*)out;

    // io mapping: lane = r4*16 + t16. One instr: rows {r4+4*it}, 16 float4
    // (=256 B) contiguous per row. Chunk k adds k*NV float4.
    const int t16 = lane & 15;
    const int r4  = lane >> 4;
    const int gq  = (rowBase + r4) * (T_LEN / 4) + t16;  // float4 units
    const int lf  = r4 * STRIDE + t16 * 4;               // float units

    // compute state
    float mem = 0.0f, refac = 2.0f, a = 0.0f, vth = 1.0f, ps = 0.0f;
    float beta_c = 0.f, p_c = 0.f, b_c = 0.f;
    const int cb = lane * STRIDE;  // compute lane's LDS row

    if (wid == 0) {
        const int n = (rowBase + lane) & (NPARAM - 1);
        beta_c = fminf(fmaxf(beta[n], 0.001f), 0.999f);
        p_c    = fminf(fabsf(p[n]), 0.999f);
        b_c    = fminf(fmaxf(fabsf(bparam[n]), 0.001f), 1.0f);
    }

    auto step = [&](float xt) -> float {
        refac = (ps > 0.0f) ? 0.0f : refac;           // spike-triggered reset
        const float ic = (refac < 2.0f) ? 0.0f : xt;  // refractory input mask
        refac += 1.0f;
        const float nm   = __fadd_rn(__fmul_rn(mem, beta_c), ic);  // integrate
        const float diff = __fsub_rn(nm, vth);
        const float s    = (diff > 0.0f) ? 1.0f : 0.0f;
        mem = (diff > 0.0f) ? 0.0f : nm;              // reset-to-zero on spike
        a   = __fadd_rn(__fmul_rn(p_c, a), s);        // adaptation
        vth = __fadd_rn(1.0f, __fmul_rn(b_c, a));     // adaptive threshold
        ps  = s;
        return s;
    };

    float4 ld[NV];  // load wave's register pipeline (one chunk ahead)

    auto loadChunk = [&](int k) {
        const int base = gq + k * NV;
        #pragma unroll
        for (int it = 0; it < NV; ++it)
            ld[it] = xv[base + it * 4 * (T_LEN / 4)];  // +4 rows per it
    };
    auto stage = [&](int buf) {   // b32 scatter into [row][65] layout
        #pragma unroll
        for (int it = 0; it < NV; ++it) {
            const int o = lf + it * 4 * STRIDE;
            inbuf[buf][o + 0] = ld[it].x;
            inbuf[buf][o + 1] = ld[it].y;
            inbuf[buf][o + 2] = ld[it].z;
            inbuf[buf][o + 3] = ld[it].w;
        }
    };
    auto drain = [&](int k) {     // outbuf -> global, 256 B/row contiguous
        const int base = gq + k * NV;
        #pragma unroll
        for (int it = 0; it < NV; ++it) {
            const int o = lf + it * 4 * STRIDE;
            float4 sv;
            sv.x = outbuf[o + 0];
            sv.y = outbuf[o + 1];
            sv.z = outbuf[o + 2];
            sv.w = outbuf[o + 3];
            ov[base + it * 4 * (T_LEN / 4)] = sv;
        }
    };

    // preamble: chunk 0 staged; chunk 1 in regs (in flight across barrier)
    if (wid == 1) {
        loadChunk(0);
        stage(0);
        loadChunk(1);
    }
    BARRIER();

    #pragma unroll 1
    for (int k = 0; k < NCHUNK; ++k) {
        const int cur = k & 1;
        float sv[CHUNK];
        // ---- phase A ----
        if (wid == 0) {
            // compute chunk k from inbuf[cur] into registers
            #pragma unroll
            for (int t = 0; t < CHUNK; ++t)
                sv[t] = step(inbuf[cur][cb + t]);
        } else if (wid == 1) {
            if (k + 1 < NCHUNK) stage(cur ^ 1);     // regs loaded one chunk ago
            if (k + 2 < NCHUNK) loadChunk(k + 2);   // refill register pipeline
        } else {
            if (k > 0) drain(k - 1);                // spikes written in k-1's B
        }
        BARRIER();  // store's outbuf reads done; inbuf[cur^1] staged
        // ---- phase B ----
        if (wid == 0) {
            #pragma unroll
            for (int t = 0; t < CHUNK; ++t)
                outbuf[cb + t] = sv[t];
        }
        BARRIER();  // outbuf[k] visible to store wave next iteration
    }
    if (wid == 2) drain(NCHUNK - 1);
}

extern "C" void kernel_launch(void* const* d_in, const int* in_sizes, int n_in,
                              void* d_out, int out_size, void* d_ws, size_t ws_size,
                              hipStream_t stream) {
    const float* x    = (const float*)d_in[0];
    const float* beta = (const float*)d_in[1];
    const float* p    = (const float*)d_in[2];
    const float* b    = (const float*)d_in[3];
    float* out        = (float*)d_out;

    const int BN = 64 * 1024;  // rows
    snn_fwd<<<dim3(BN / ROWS), dim3(192), 0, stream>>>(x, beta, p, b, out);
}